// Round 3
// baseline (178.313 us; speedup 1.0000x reference)
//
#include <hip/hip_runtime.h>
#include <math.h>

#define NN 10000
#define NE 160000
// Only the l=0 irrep reaches the output (scal takes cols h*72..h*72+8 of pooled,
// which come solely from node_out[:,:,0]; Y[:,0]==1). l=1/l=2 paths are dead.
//
// Round 3: CSR-ordered edge payload, pre-multiplied by x[src].
//   - k_edge fuses logit/wv0 compute + CSR scatter: stores lgp/wxs at slot p.
//   - k_gather streams contiguous ranges: no eid indirection, no x gather,
//     no cross-lane reduce (16 lanes per (node,head), lane == channel).
//   - zeroing fused into k_xqk; 7 launches total.
//
// Workspace (floats):
//   x      [10000][16]        @ 0
//   q      [10000][2][16]     @ 160000
//   k      [10000][2][16]     @ 480000
//   lgp    [160000][2]        @ 800000    (CSR slot-ordered logits)
//   wxs    [160000][2][16]    @ 1120000   (CSR slot-ordered wv0*x[src])
//   feat   [10000][16]        @ 6240000
//   pooled [16][16]           @ 6400000
//   deg    int[10000]                     (pooled..deg zeroed together)
//   row    int[10001]
//   cur    int[10000]

// x = nf @ We + be ; q[h] = x @ Wq[h] ; k[h] = x @ Wk[h]; also zeroes pooled+deg
__global__ __launch_bounds__(256) void k_xqk(const float* __restrict__ nf,
        const float* __restrict__ We, const float* __restrict__ be,
        const float* __restrict__ Wq, const float* __restrict__ Wk,
        float* __restrict__ x, float* __restrict__ q, float* __restrict__ k,
        int* __restrict__ zeroReg) {
    int t = threadIdx.x;
    int gid = blockIdx.x * 256 + t;
    if (gid < 10256) zeroReg[gid] = 0;   // pooled(256f)+deg(10000i), contiguous
    __shared__ float sWe[64 * 16];
    __shared__ float sWq[2 * 16 * 16];
    __shared__ float sWk[2 * 16 * 16];
    __shared__ float sNF[16 * 64];
    __shared__ float sX[16 * 16];
    for (int i = t; i < 1024; i += 256) sWe[i] = We[i];
    for (int i = t; i < 512; i += 256) { sWq[i] = Wq[i]; sWk[i] = Wk[i]; }
    int nodeBase = blockIdx.x * 16;
    for (int i = t; i < 1024; i += 256) {
        int n = nodeBase + (i >> 6);
        sNF[i] = (n < NN) ? nf[n * 64 + (i & 63)] : 0.0f;
    }
    __syncthreads();
    int ln = t >> 4, c = t & 15;
    int n = nodeBase + ln;
    float acc = be[c];
    #pragma unroll 16
    for (int j = 0; j < 64; ++j) acc = fmaf(sNF[ln * 64 + j], sWe[j * 16 + c], acc);
    sX[ln * 16 + c] = acc;
    __syncthreads();
    if (n < NN) {
        x[n * 16 + c] = acc;
        #pragma unroll
        for (int h = 0; h < 2; ++h) {
            float aq = 0.0f, ak = 0.0f;
            #pragma unroll
            for (int j = 0; j < 16; ++j) {
                float xv = sX[ln * 16 + j];
                aq = fmaf(xv, sWq[(h * 16 + j) * 16 + c], aq);
                ak = fmaf(xv, sWk[(h * 16 + j) * 16 + c], ak);
            }
            q[(n * 2 + h) * 16 + c] = aq;
            k[(n * 2 + h) * 16 + c] = ak;
        }
    }
}

__global__ __launch_bounds__(256) void k_hist(const int* __restrict__ ei, int* __restrict__ deg) {
    int e = blockIdx.x * 256 + threadIdx.x;
    if (e < NE) atomicAdd(&deg[ei[NE + e]], 1);
}

// exclusive scan of deg[10000] -> row[10001]; copy to cur
__global__ __launch_bounds__(1024) void k_scan(const int* __restrict__ deg,
        int* __restrict__ row, int* __restrict__ cur) {
    __shared__ int sP[1024];
    int t = threadIdx.x;
    int base = t * 10;
    int loc[10];
    int sum = 0;
    #pragma unroll
    for (int j = 0; j < 10; ++j) {
        int v = (base + j < NN) ? deg[base + j] : 0;
        loc[j] = sum; sum += v;
    }
    sP[t] = sum;
    __syncthreads();
    for (int off = 1; off < 1024; off <<= 1) {
        int v = (t >= off) ? sP[t - off] : 0;
        __syncthreads();
        sP[t] += v;
        __syncthreads();
    }
    int start = sP[t] - sum;
    #pragma unroll
    for (int j = 0; j < 10; ++j) {
        if (base + j < NN) { int r = start + loc[j]; row[base + j] = r; cur[base + j] = r; }
    }
    if (t == 1023) row[NN] = sP[1023];
}

// per edge: logits + wv0, scatter into CSR slot p: lgp[p][h], wxs[p][h][c]=wv0*x[s][c]
__global__ __launch_bounds__(256) void k_edge(const float* __restrict__ pos,
        const int* __restrict__ ei,
        const float* __restrict__ q, const float* __restrict__ k,
        const float* __restrict__ W1, const float* __restrict__ b1,
        const float* __restrict__ Wa, const float* __restrict__ Wv,
        const float* __restrict__ x, int* __restrict__ cur,
        float* __restrict__ lgp, float* __restrict__ wxs) {
    __shared__ float sW1[128], sB1[128], sWa[128];
    __shared__ float sV[2048];   // [h][j][c] compacted Wv[:, ::3]
    int t0 = threadIdx.x;
    if (t0 < 128) { sW1[t0] = W1[t0]; sB1[t0] = b1[t0]; sWa[t0] = Wa[t0]; }
    for (int i = t0; i < 2048; i += 256) {
        int h = i >> 10, j = (i >> 4) & 63, c = i & 15;
        sV[i] = Wv[(h * 64 + j) * 48 + 3 * c];
    }
    __syncthreads();
    int e = blockIdx.x * 256 + t0;
    if (e >= NE) return;
    int s = ei[e], t = ei[NE + e];
    int p = atomicAdd(&cur[t], 1);
    float dx = pos[t * 3 + 0] - pos[s * 3 + 0];
    float dy = pos[t * 3 + 1] - pos[s * 3 + 1];
    float dz = pos[t * 3 + 2] - pos[s * 3 + 2];
    float d = sqrtf(dx * dx + dy * dy + dz * dz);
    float fh[2] = { d, 1.0f / (d * d) };
    const float4* qt = (const float4*)(q + (size_t)t * 32);
    const float4* ks = (const float4*)(k + (size_t)s * 32);
    const float4* xp = (const float4*)(x + (size_t)s * 16);
    float4 xs[4] = { xp[0], xp[1], xp[2], xp[3] };
    float L2v[2];
    float4* wp = (float4*)(wxs + (size_t)p * 32);
    #pragma unroll
    for (int h = 0; h < 2; ++h) {
        float4 a0 = qt[h * 4 + 0], a1 = qt[h * 4 + 1], a2 = qt[h * 4 + 2], a3 = qt[h * 4 + 3];
        float4 b0 = ks[h * 4 + 0], c1 = ks[h * 4 + 1], c2 = ks[h * 4 + 2], c3 = ks[h * 4 + 3];
        float dot = a0.x * b0.x + a0.y * b0.y + a0.z * b0.z + a0.w * b0.w
                  + a1.x * c1.x + a1.y * c1.y + a1.z * c1.z + a1.w * c1.w
                  + a2.x * c2.x + a2.y * c2.y + a2.z * c2.z + a2.w * c2.w
                  + a3.x * c3.x + a3.y * c3.y + a3.z * c3.z + a3.w * c3.w;
        float f = fh[h];
        float att = 0.0f;
        float acc[16];
        #pragma unroll
        for (int c = 0; c < 16; ++c) acc[c] = 0.0f;
        const float4* vp = (const float4*)(sV + h * 1024);
        for (int j = 0; j < 64; ++j) {
            float hj = fmaxf(fmaf(f, sW1[h * 64 + j], sB1[h * 64 + j]), 0.0f);
            att = fmaf(hj, sWa[h * 64 + j], att);
            float4 v0 = vp[j * 4 + 0], v1 = vp[j * 4 + 1], v2 = vp[j * 4 + 2], v3 = vp[j * 4 + 3];
            acc[0]  = fmaf(hj, v0.x, acc[0]);  acc[1]  = fmaf(hj, v0.y, acc[1]);
            acc[2]  = fmaf(hj, v0.z, acc[2]);  acc[3]  = fmaf(hj, v0.w, acc[3]);
            acc[4]  = fmaf(hj, v1.x, acc[4]);  acc[5]  = fmaf(hj, v1.y, acc[5]);
            acc[6]  = fmaf(hj, v1.z, acc[6]);  acc[7]  = fmaf(hj, v1.w, acc[7]);
            acc[8]  = fmaf(hj, v2.x, acc[8]);  acc[9]  = fmaf(hj, v2.y, acc[9]);
            acc[10] = fmaf(hj, v2.z, acc[10]); acc[11] = fmaf(hj, v2.w, acc[11]);
            acc[12] = fmaf(hj, v3.x, acc[12]); acc[13] = fmaf(hj, v3.y, acc[13]);
            acc[14] = fmaf(hj, v3.z, acc[14]); acc[15] = fmaf(hj, v3.w, acc[15]);
        }
        L2v[h] = fmaf(dot, 0.25f, att);
        wp[h * 4 + 0] = make_float4(acc[0] * xs[0].x, acc[1] * xs[0].y, acc[2] * xs[0].z, acc[3] * xs[0].w);
        wp[h * 4 + 1] = make_float4(acc[4] * xs[1].x, acc[5] * xs[1].y, acc[6] * xs[1].z, acc[7] * xs[1].w);
        wp[h * 4 + 2] = make_float4(acc[8] * xs[2].x, acc[9] * xs[2].y, acc[10] * xs[2].z, acc[11] * xs[2].w);
        wp[h * 4 + 3] = make_float4(acc[12] * xs[3].x, acc[13] * xs[3].y, acc[14] * xs[3].z, acc[15] * xs[3].w);
    }
    *(float2*)(lgp + (size_t)p * 2) = make_float2(L2v[0], L2v[1]);
}

// 16 lanes per (node,head): stream [rs,re), lane == channel; no reductions.
__global__ __launch_bounds__(256) void k_gather(const int* __restrict__ row,
        const float* __restrict__ lgp, const float* __restrict__ wxs,
        const float* __restrict__ Wo, float* __restrict__ feat) {
    __shared__ float sWo[256];     // [h][c][o] = Wo[h*384 + c*8 + o]
    __shared__ float sUn[16][16];
    int t0 = threadIdx.x;
    sWo[t0] = Wo[(t0 >> 7) * 384 + (t0 & 127)];
    __syncthreads();
    int lp = t0 >> 4;                       // local pair 0..15
    int c  = t0 & 15;
    int pid = blockIdx.x * 16 + lp;         // (node,head) pair, grid exact
    int n = pid >> 1, h = pid & 1;
    int rs = row[n], re = row[n + 1];
    float m = -INFINITY;
    for (int i = rs; i < re; ++i) m = fmaxf(m, lgp[i * 2 + h]);
    float z = 0.0f, u = 0.0f;
    for (int i = rs; i < re; ++i) {
        float w = __expf(lgp[i * 2 + h] - m);
        u = fmaf(w, wxs[(size_t)i * 32 + h * 16 + c], u);
        z += w;
    }
    float un = (z > 0.0f) ? u / z : 0.0f;
    sUn[lp][c] = un;                        // same-wave LDS round trip
    if (c < 8) {
        float o_acc = 0.0f;
        #pragma unroll
        for (int cc = 0; cc < 16; ++cc)
            o_acc = fmaf(sUn[lp][cc], sWo[h * 128 + cc * 8 + c], o_acc);
        feat[n * 16 + h * 8 + c] = o_acc;
    }
}

// pooled[g][hc] += feat[n][hc] for batch[n]==g; LDS pre-aggregation, 40 blocks
__global__ __launch_bounds__(256) void k_pool(const float* __restrict__ feat,
        const int* __restrict__ batch, float* __restrict__ pooled) {
    __shared__ float sP[256];
    int t = threadIdx.x;
    sP[t] = 0.0f;
    __syncthreads();
    for (int i = blockIdx.x * 256 + t; i < NN * 16; i += 40 * 256) {
        int n = i >> 4, c = i & 15;
        atomicAdd(&sP[batch[n] * 16 + c], feat[i]);
    }
    __syncthreads();
    atomicAdd(&pooled[t], sP[t]);
}

__global__ __launch_bounds__(512) void k_final(const float* __restrict__ pooled,
        const float* __restrict__ Wproj, const float* __restrict__ bproj,
        float* __restrict__ out) {
    int t = threadIdx.x;
    int g = t >> 5, fo = t & 31;
    float acc = bproj[fo];
    #pragma unroll
    for (int j = 0; j < 16; ++j) acc = fmaf(pooled[g * 16 + j], Wproj[j * 32 + fo], acc);
    out[g * 32 + fo] = acc;
}

extern "C" void kernel_launch(void* const* d_in, const int* in_sizes, int n_in,
                              void* d_out, int out_size, void* d_ws, size_t ws_size,
                              hipStream_t stream) {
    const float* nf    = (const float*)d_in[0];
    const float* pos   = (const float*)d_in[1];
    const float* We    = (const float*)d_in[2];
    const float* be    = (const float*)d_in[3];
    const float* Wq    = (const float*)d_in[4];
    const float* Wk    = (const float*)d_in[5];
    const float* W1    = (const float*)d_in[6];
    const float* b1    = (const float*)d_in[7];
    const float* Wa    = (const float*)d_in[8];
    const float* Wv    = (const float*)d_in[9];
    const float* Wo    = (const float*)d_in[10];
    const float* Wproj = (const float*)d_in[11];
    const float* bproj = (const float*)d_in[12];
    const int*   ei    = (const int*)d_in[13];
    const int*   batch = (const int*)d_in[14];
    float* out = (float*)d_out;
    (void)in_sizes; (void)n_in; (void)out_size; (void)ws_size;

    float* ws     = (float*)d_ws;
    float* x      = ws;                  // 160000
    float* q      = x + 160000;          // 320000
    float* k      = q + 320000;          // 320000
    float* lgp    = k + 320000;          // 320000
    float* wxs    = lgp + 320000;        // 5120000
    float* feat   = wxs + 5120000;       // 160000
    float* pooled = feat + 160000;       // 256
    int*   deg    = (int*)(pooled + 256);
    int*   row    = deg + 10000;
    int*   cur    = row + 10001;

    hipLaunchKernelGGL(k_xqk,    dim3(625),  dim3(256),  0, stream, nf, We, be, Wq, Wk, x, q, k, (int*)pooled);
    hipLaunchKernelGGL(k_hist,   dim3(625),  dim3(256),  0, stream, ei, deg);
    hipLaunchKernelGGL(k_scan,   dim3(1),    dim3(1024), 0, stream, deg, row, cur);
    hipLaunchKernelGGL(k_edge,   dim3(625),  dim3(256),  0, stream, pos, ei, q, k, W1, b1, Wa, Wv, x, cur, lgp, wxs);
    hipLaunchKernelGGL(k_gather, dim3(1250), dim3(256),  0, stream, row, lgp, wxs, Wo, feat);
    hipLaunchKernelGGL(k_pool,   dim3(40),   dim3(256),  0, stream, feat, batch, pooled);
    hipLaunchKernelGGL(k_final,  dim3(1),    dim3(512),  0, stream, pooled, Wproj, bproj, out);
}

// Round 4
// 139.686 us; speedup vs baseline: 1.2765x; 1.2765x over previous
//
#include <hip/hip_runtime.h>
#include <math.h>

#define NN 10000
#define NE 160000
#define CAP 96   // per-node edge bin capacity; deg ~ Poisson(16), +20 sigma
// Only the l=0 irrep reaches the output (scal takes cols h*72..h*72+8 of pooled,
// which come solely from node_out[:,:,0]; Y[:,0]==1). l=1/l=2 paths are dead.
//
// Round 4: fixed-capacity bins (no hist/scan CSR build) + single-pass online
// softmax gather with 4-way edge parallelism. 5 dispatches.
//
// Workspace (floats):
//   x      [10000][16]        @ 0
//   q      [10000][2][16]     @ 160000
//   k      [10000][2][16]     @ 480000
//   feat   [10000][16]        @ 800000
//   pooled [16][16]           @ 960000
//   deg    int[10000]         @ 960256   (pooled..deg zeroed together)
//   lgp    [10000][96][2]     @ 970256
//   wxs    [10000][96][2][16] @ 2890256
// total ~134.4 MB

// x = nf @ We + be ; q[h] = x @ Wq[h] ; k[h] = x @ Wk[h]; zeroes pooled+deg
__global__ __launch_bounds__(256) void k_xqk(const float* __restrict__ nf,
        const float* __restrict__ We, const float* __restrict__ be,
        const float* __restrict__ Wq, const float* __restrict__ Wk,
        float* __restrict__ x, float* __restrict__ q, float* __restrict__ k,
        int* __restrict__ zeroReg) {
    int t = threadIdx.x;
    int gid = blockIdx.x * 256 + t;
    if (gid < 10256) zeroReg[gid] = 0;   // pooled(256f)+deg(10000i), contiguous
    __shared__ float sWe[64 * 16];
    __shared__ float sWq[2 * 16 * 16];
    __shared__ float sWk[2 * 16 * 16];
    __shared__ float sNF[16 * 64];
    __shared__ float sX[16 * 16];
    for (int i = t; i < 1024; i += 256) sWe[i] = We[i];
    for (int i = t; i < 512; i += 256) { sWq[i] = Wq[i]; sWk[i] = Wk[i]; }
    int nodeBase = blockIdx.x * 16;
    for (int i = t; i < 1024; i += 256) {
        int n = nodeBase + (i >> 6);
        sNF[i] = (n < NN) ? nf[n * 64 + (i & 63)] : 0.0f;
    }
    __syncthreads();
    int ln = t >> 4, c = t & 15;
    int n = nodeBase + ln;
    float acc = be[c];
    #pragma unroll 16
    for (int j = 0; j < 64; ++j) acc = fmaf(sNF[ln * 64 + j], sWe[j * 16 + c], acc);
    sX[ln * 16 + c] = acc;
    __syncthreads();
    if (n < NN) {
        x[n * 16 + c] = acc;
        #pragma unroll
        for (int h = 0; h < 2; ++h) {
            float aq = 0.0f, ak = 0.0f;
            #pragma unroll
            for (int j = 0; j < 16; ++j) {
                float xv = sX[ln * 16 + j];
                aq = fmaf(xv, sWq[(h * 16 + j) * 16 + c], aq);
                ak = fmaf(xv, sWk[(h * 16 + j) * 16 + c], ak);
            }
            q[(n * 2 + h) * 16 + c] = aq;
            k[(n * 2 + h) * 16 + c] = ak;
        }
    }
}

// per edge: logits + wv0*x[src]; write into bin slot tgt*CAP + p
__global__ __launch_bounds__(256) void k_edge(const float* __restrict__ pos,
        const int* __restrict__ ei,
        const float* __restrict__ q, const float* __restrict__ k,
        const float* __restrict__ W1, const float* __restrict__ b1,
        const float* __restrict__ Wa, const float* __restrict__ Wv,
        const float* __restrict__ x, int* __restrict__ deg,
        float* __restrict__ lgp, float* __restrict__ wxs) {
    __shared__ float sW1[128], sB1[128], sWa[128];
    __shared__ float sV[2048];   // [h][j][c] compacted Wv[:, ::3]
    int t0 = threadIdx.x;
    if (t0 < 128) { sW1[t0] = W1[t0]; sB1[t0] = b1[t0]; sWa[t0] = Wa[t0]; }
    for (int i = t0; i < 2048; i += 256) {
        int h = i >> 10, j = (i >> 4) & 63, c = i & 15;
        sV[i] = Wv[(h * 64 + j) * 48 + 3 * c];
    }
    __syncthreads();
    int e = blockIdx.x * 256 + t0;
    if (e >= NE) return;
    int s = ei[e], t = ei[NE + e];
    int p = atomicAdd(&deg[t], 1);
    bool ok = (p < CAP);
    size_t slot = (size_t)t * CAP + p;
    float dx = pos[t * 3 + 0] - pos[s * 3 + 0];
    float dy = pos[t * 3 + 1] - pos[s * 3 + 1];
    float dz = pos[t * 3 + 2] - pos[s * 3 + 2];
    float d = sqrtf(dx * dx + dy * dy + dz * dz);
    float fh[2] = { d, 1.0f / (d * d) };
    const float4* qt = (const float4*)(q + (size_t)t * 32);
    const float4* ks = (const float4*)(k + (size_t)s * 32);
    const float4* xp = (const float4*)(x + (size_t)s * 16);
    float4 xs[4] = { xp[0], xp[1], xp[2], xp[3] };
    float L2v[2];
    float4* wp = (float4*)(wxs + slot * 32);
    #pragma unroll
    for (int h = 0; h < 2; ++h) {
        float4 a0 = qt[h * 4 + 0], a1 = qt[h * 4 + 1], a2 = qt[h * 4 + 2], a3 = qt[h * 4 + 3];
        float4 b0 = ks[h * 4 + 0], c1 = ks[h * 4 + 1], c2 = ks[h * 4 + 2], c3 = ks[h * 4 + 3];
        float dot = a0.x * b0.x + a0.y * b0.y + a0.z * b0.z + a0.w * b0.w
                  + a1.x * c1.x + a1.y * c1.y + a1.z * c1.z + a1.w * c1.w
                  + a2.x * c2.x + a2.y * c2.y + a2.z * c2.z + a2.w * c2.w
                  + a3.x * c3.x + a3.y * c3.y + a3.z * c3.z + a3.w * c3.w;
        float f = fh[h];
        float att = 0.0f;
        float acc[16];
        #pragma unroll
        for (int c = 0; c < 16; ++c) acc[c] = 0.0f;
        const float4* vp = (const float4*)(sV + h * 1024);
        for (int j = 0; j < 64; ++j) {
            float hj = fmaxf(fmaf(f, sW1[h * 64 + j], sB1[h * 64 + j]), 0.0f);
            att = fmaf(hj, sWa[h * 64 + j], att);
            float4 v0 = vp[j * 4 + 0], v1 = vp[j * 4 + 1], v2 = vp[j * 4 + 2], v3 = vp[j * 4 + 3];
            acc[0]  = fmaf(hj, v0.x, acc[0]);  acc[1]  = fmaf(hj, v0.y, acc[1]);
            acc[2]  = fmaf(hj, v0.z, acc[2]);  acc[3]  = fmaf(hj, v0.w, acc[3]);
            acc[4]  = fmaf(hj, v1.x, acc[4]);  acc[5]  = fmaf(hj, v1.y, acc[5]);
            acc[6]  = fmaf(hj, v1.z, acc[6]);  acc[7]  = fmaf(hj, v1.w, acc[7]);
            acc[8]  = fmaf(hj, v2.x, acc[8]);  acc[9]  = fmaf(hj, v2.y, acc[9]);
            acc[10] = fmaf(hj, v2.z, acc[10]); acc[11] = fmaf(hj, v2.w, acc[11]);
            acc[12] = fmaf(hj, v3.x, acc[12]); acc[13] = fmaf(hj, v3.y, acc[13]);
            acc[14] = fmaf(hj, v3.z, acc[14]); acc[15] = fmaf(hj, v3.w, acc[15]);
        }
        L2v[h] = fmaf(dot, 0.25f, att);
        if (ok) {
            wp[h * 4 + 0] = make_float4(acc[0] * xs[0].x, acc[1] * xs[0].y, acc[2] * xs[0].z, acc[3] * xs[0].w);
            wp[h * 4 + 1] = make_float4(acc[4] * xs[1].x, acc[5] * xs[1].y, acc[6] * xs[1].z, acc[7] * xs[1].w);
            wp[h * 4 + 2] = make_float4(acc[8] * xs[2].x, acc[9] * xs[2].y, acc[10] * xs[2].z, acc[11] * xs[2].w);
            wp[h * 4 + 3] = make_float4(acc[12] * xs[3].x, acc[13] * xs[3].y, acc[14] * xs[3].z, acc[15] * xs[3].w);
        }
    }
    if (ok) *(float2*)(lgp + slot * 2) = make_float2(L2v[0], L2v[1]);
}

// wave per (node,head): 4 edge-groups x 16 channels, single-pass online softmax.
__global__ __launch_bounds__(256) void k_gather(const int* __restrict__ deg,
        const float* __restrict__ lgp, const float* __restrict__ wxs,
        const float* __restrict__ Wo, float* __restrict__ feat) {
    __shared__ float sWo[256];     // [h][c][o] = Wo[h*384 + c*8 + o]
    __shared__ float sUn[4][16];
    int t0 = threadIdx.x;
    sWo[t0] = Wo[(t0 >> 7) * 384 + (t0 & 127)];
    __syncthreads();
    int wv = t0 >> 6;                     // wave in block 0..3
    int lane = t0 & 63;
    int pid = blockIdx.x * 4 + wv;        // (node,head) pair; grid exact
    int n = pid >> 1, h = pid & 1;
    int dg = min(deg[n], CAP);
    int g = lane >> 4, c = lane & 15;
    float m = -INFINITY, z = 0.0f, u = 0.0f;
    const float* lgb = lgp + (size_t)n * (CAP * 2) + h;
    const float* wxb = wxs + (size_t)n * (CAP * 32) + h * 16 + c;
    for (int i = g; i < dg; i += 4) {
        float L  = lgb[i * 2];
        float wx = wxb[(size_t)i * 32];
        float nm = fmaxf(m, L);
        float sc = __expf(m - nm);
        float w  = __expf(L - nm);
        u = fmaf(u, sc, w * wx);
        z = fmaf(z, sc, w);
        m = nm;
    }
    // merge the 4 groups (lane^16, lane^32 preserve channel bits)
    #pragma unroll
    for (int off = 16; off <= 32; off <<= 1) {
        float mo = __shfl_xor(m, off, 64);
        float zo = __shfl_xor(z, off, 64);
        float uo = __shfl_xor(u, off, 64);
        float nm = fmaxf(m, mo);
        float a = __expf(m - nm), b = __expf(mo - nm);
        u = u * a + uo * b;
        z = z * a + zo * b;
        m = nm;
    }
    float un = (z > 0.0f) ? u / z : 0.0f;   // NaN-z (empty) -> 0
    sUn[wv][c] = un;                        // 4 lanes same value, benign
    if (lane < 8) {
        float o_acc = 0.0f;
        #pragma unroll
        for (int cc = 0; cc < 16; ++cc)
            o_acc = fmaf(sUn[wv][cc], sWo[h * 128 + cc * 8 + lane], o_acc);
        feat[n * 16 + h * 8 + lane] = o_acc;
    }
}

// pooled[g][hc] += feat[n][hc] for batch[n]==g; LDS pre-aggregation, 40 blocks
__global__ __launch_bounds__(256) void k_pool(const float* __restrict__ feat,
        const int* __restrict__ batch, float* __restrict__ pooled) {
    __shared__ float sP[256];
    int t = threadIdx.x;
    sP[t] = 0.0f;
    __syncthreads();
    for (int i = blockIdx.x * 256 + t; i < NN * 16; i += 40 * 256) {
        int n = i >> 4, c = i & 15;
        atomicAdd(&sP[batch[n] * 16 + c], feat[i]);
    }
    __syncthreads();
    atomicAdd(&pooled[t], sP[t]);
}

__global__ __launch_bounds__(512) void k_final(const float* __restrict__ pooled,
        const float* __restrict__ Wproj, const float* __restrict__ bproj,
        float* __restrict__ out) {
    int t = threadIdx.x;
    int g = t >> 5, fo = t & 31;
    float acc = bproj[fo];
    #pragma unroll
    for (int j = 0; j < 16; ++j) acc = fmaf(pooled[g * 16 + j], Wproj[j * 32 + fo], acc);
    out[g * 32 + fo] = acc;
}

extern "C" void kernel_launch(void* const* d_in, const int* in_sizes, int n_in,
                              void* d_out, int out_size, void* d_ws, size_t ws_size,
                              hipStream_t stream) {
    const float* nf    = (const float*)d_in[0];
    const float* pos   = (const float*)d_in[1];
    const float* We    = (const float*)d_in[2];
    const float* be    = (const float*)d_in[3];
    const float* Wq    = (const float*)d_in[4];
    const float* Wk    = (const float*)d_in[5];
    const float* W1    = (const float*)d_in[6];
    const float* b1    = (const float*)d_in[7];
    const float* Wa    = (const float*)d_in[8];
    const float* Wv    = (const float*)d_in[9];
    const float* Wo    = (const float*)d_in[10];
    const float* Wproj = (const float*)d_in[11];
    const float* bproj = (const float*)d_in[12];
    const int*   ei    = (const int*)d_in[13];
    const int*   batch = (const int*)d_in[14];
    float* out = (float*)d_out;
    (void)in_sizes; (void)n_in; (void)out_size; (void)ws_size;

    float* ws     = (float*)d_ws;
    float* x      = ws;                  // 160000
    float* q      = x + 160000;          // 320000
    float* k      = q + 320000;          // 320000
    float* feat   = k + 320000;          // 160000
    float* pooled = feat + 160000;       // 256
    int*   deg    = (int*)(pooled + 256);// 10000
    float* lgp    = (float*)(deg + 10000);   // 1,920,000
    float* wxs    = lgp + (size_t)NN * CAP * 2;  // 30,720,000

    hipLaunchKernelGGL(k_xqk,    dim3(625),  dim3(256), 0, stream, nf, We, be, Wq, Wk, x, q, k, (int*)pooled);
    hipLaunchKernelGGL(k_edge,   dim3(625),  dim3(256), 0, stream, pos, ei, q, k, W1, b1, Wa, Wv, x, deg, lgp, wxs);
    hipLaunchKernelGGL(k_gather, dim3(5000), dim3(256), 0, stream, deg, lgp, wxs, Wo, feat);
    hipLaunchKernelGGL(k_pool,   dim3(40),   dim3(256), 0, stream, feat, batch, pooled);
    hipLaunchKernelGGL(k_final,  dim3(1),    dim3(512), 0, stream, pooled, Wproj, bproj, out);
}